// Round 1
// baseline (830.437 us; speedup 1.0000x reference)
//
#include <hip/hip_runtime.h>
#include <cmath>

// B=2, L=2048, DIM=1024, NH=16, HD=64
typedef _Float16 half8 __attribute__((ext_vector_type(8)));
typedef _Float16 half4 __attribute__((ext_vector_type(4)));
typedef float f32x4 __attribute__((ext_vector_type(4)));

#define NEGBIG (-3.4028235e38f)

// ---------------- cast x: f32 -> f16 ----------------
__global__ void cast4_kernel(const float* __restrict__ in, _Float16* __restrict__ out, int n) {
    int i = (blockIdx.x * 256 + threadIdx.x) * 4;
    if (i < n) {
        float4 v = *(const float4*)&in[i];
        half4 o = { (_Float16)v.x, (_Float16)v.y, (_Float16)v.z, (_Float16)v.w };
        *(half4*)&out[i] = o;
    }
}

// ---------------- transpose+cast weight: W[k][n] f32 -> Wt[n][k] f16 ----------------
__global__ void transpose_cast_kernel(const float* __restrict__ W, _Float16* __restrict__ Wt) {
    __shared__ float tile[32][33];
    int bx = blockIdx.x * 32;  // k base
    int by = blockIdx.y * 32;  // n base
    int tx = threadIdx.x & 31, ty = threadIdx.x >> 5;  // ty 0..7
    #pragma unroll
    for (int r = 0; r < 32; r += 8)
        tile[ty + r][tx] = W[(size_t)(bx + ty + r) * 1024 + by + tx];
    __syncthreads();
    #pragma unroll
    for (int r = 0; r < 32; r += 8)
        Wt[(size_t)(by + ty + r) * 1024 + bx + tx] = (_Float16)tile[tx][ty + r];
}

// ---------------- fused QKV GEMM: X[4096][1024]f16 @ W -> Q/K head-major, V transposed ----------------
// z=0: Q -> Qh[b][h][l][d]; z=1: K -> Kh[b][h][l][d]; z=2: V -> VTh[b][h][d][l]
__global__ __launch_bounds__(256)
void gemm_qkv_kernel(const _Float16* __restrict__ X,
                     const _Float16* __restrict__ WqT, const _Float16* __restrict__ WkT,
                     const _Float16* __restrict__ WvT,
                     _Float16* __restrict__ Qh, _Float16* __restrict__ Kh, _Float16* __restrict__ VTh)
{
    const int z = blockIdx.z;
    const _Float16* __restrict__ Bt = (z == 0) ? WqT : (z == 1) ? WkT : WvT;
    _Float16* __restrict__ out      = (z == 0) ? Qh  : (z == 1) ? Kh  : VTh;

    __shared__ _Float16 Asb[128][40];
    __shared__ _Float16 Bsb[128][40];

    const int tid = threadIdx.x;
    const int bm = blockIdx.x * 128;
    const int bn = blockIdx.y * 128;
    const int wave = tid >> 6, lane = tid & 63;
    const int wm = (wave >> 1) * 64, wn = (wave & 1) * 64;
    const int quad = lane >> 4, l16 = lane & 15;

    f32x4 acc[4][4] = {};

    for (int k0 = 0; k0 < 1024; k0 += 32) {
        #pragma unroll
        for (int c = 0; c < 2; ++c) {
            int chunk = tid + c * 256;           // 0..511
            int row = chunk >> 2;                // 0..127
            int kc  = (chunk & 3) * 8;           // 0,8,16,24
            *(half8*)&Asb[row][kc] = *(const half8*)&X [(size_t)(bm + row) * 1024 + k0 + kc];
            *(half8*)&Bsb[row][kc] = *(const half8*)&Bt[(size_t)(bn + row) * 1024 + k0 + kc];
        }
        __syncthreads();
        half8 af[4], bf[4];
        #pragma unroll
        for (int mt = 0; mt < 4; ++mt) af[mt] = *(const half8*)&Asb[wm + mt*16 + l16][quad * 8];
        #pragma unroll
        for (int nt = 0; nt < 4; ++nt) bf[nt] = *(const half8*)&Bsb[wn + nt*16 + l16][quad * 8];
        #pragma unroll
        for (int mt = 0; mt < 4; ++mt)
            #pragma unroll
            for (int nt = 0; nt < 4; ++nt)
                acc[mt][nt] = __builtin_amdgcn_mfma_f32_16x16x32_f16(af[mt], bf[nt], acc[mt][nt], 0, 0, 0);
        __syncthreads();
    }

    // epilogue: C/D layout col=lane&15, row=quad*4+reg
    #pragma unroll
    for (int mt = 0; mt < 4; ++mt) {
        #pragma unroll
        for (int nt = 0; nt < 4; ++nt) {
            #pragma unroll
            for (int r = 0; r < 4; ++r) {
                int m = bm + wm + mt * 16 + quad * 4 + r;   // row index in [0,4096): b*L+l
                int n = bn + wn + nt * 16 + l16;            // col index in [0,1024): h*64+d
                _Float16 hv = (_Float16)acc[mt][nt][r];
                int bb = m >> 11, ll = m & 2047, hh = n >> 6, dd = n & 63;
                if (z < 2)
                    out[(((size_t)(bb * 16 + hh)) * 2048 + ll) * 64 + dd] = hv;
                else
                    out[(((size_t)(bb * 16 + hh)) * 64 + dd) * 2048 + ll] = hv;
            }
        }
    }
}

// ---------------- flash attention with additive bias + key mask ----------------
__device__ __forceinline__ float rowmax16(float v) {
    #pragma unroll
    for (int off = 1; off < 16; off <<= 1) v = fmaxf(v, __shfl_xor(v, off));
    return v;
}
__device__ __forceinline__ float rowsum16(float v) {
    #pragma unroll
    for (int off = 1; off < 16; off <<= 1) v += __shfl_xor(v, off);
    return v;
}

__global__ __launch_bounds__(256)
void flash_attn_kernel(const _Float16* __restrict__ Qh, const _Float16* __restrict__ Kh,
                       const _Float16* __restrict__ VTh, const float* __restrict__ bias,
                       const int* __restrict__ mask, _Float16* __restrict__ AO)
{
    const int qt = blockIdx.x, h = blockIdx.y, b = blockIdx.z;
    const int tid = threadIdx.x, wave = tid >> 6, lane = tid & 63;
    const int quad = lane >> 4, l16 = lane & 15;

    __shared__ _Float16 Kt[64][72];      // [j][d]
    __shared__ _Float16 Vt[64][72];      // [d][j]
    __shared__ _Float16 Pw[4][16][72];   // per-wave P: [i][j]

    const size_t head = (size_t)(b * 16 + h) * 2048 * 64;
    const int i_base = qt * 64 + wave * 16;
    const int ig0 = i_base + quad * 4;

    // Q fragments (A-layout: m=lane&15, k=quad*8+j)
    half8 qf0 = *(const half8*)&Qh[head + (size_t)(i_base + l16) * 64 + quad * 8];
    half8 qf1 = *(const half8*)&Qh[head + (size_t)(i_base + l16) * 64 + 32 + quad * 8];

    float m_r[4] = { -INFINITY, -INFINITY, -INFINITY, -INFINITY };
    float l_r[4] = {};
    f32x4 o[4] = {};

    for (int j0 = 0; j0 < 2048; j0 += 64) {
        #pragma unroll
        for (int c = 0; c < 2; ++c) {
            int chunk = tid + c * 256;          // 0..511
            int row = chunk >> 3;               // 0..63
            int dc  = (chunk & 7) * 8;          // 0..56
            *(half8*)&Kt[row][dc] = *(const half8*)&Kh [head + (size_t)(j0 + row) * 64 + dc];
            *(half8*)&Vt[row][dc] = *(const half8*)&VTh[head + (size_t)row * 2048 + j0 + dc];
        }
        __syncthreads();

        float sreg[4][4];
        #pragma unroll
        for (int jt = 0; jt < 4; ++jt) {
            half8 kf0 = *(const half8*)&Kt[jt * 16 + l16][quad * 8];
            half8 kf1 = *(const half8*)&Kt[jt * 16 + l16][32 + quad * 8];
            f32x4 s = {};
            s = __builtin_amdgcn_mfma_f32_16x16x32_f16(qf0, kf0, s, 0, 0, 0);
            s = __builtin_amdgcn_mfma_f32_16x16x32_f16(qf1, kf1, s, 0, 0, 0);
            int jg = j0 + jt * 16 + l16;
            int mv = mask[b * 2048 + jg];
            const float* bp = bias + ((size_t)((b * 16 + h) * 2048 + ig0)) * 2048 + jg;
            #pragma unroll
            for (int r = 0; r < 4; ++r) {
                float bv = bp[(size_t)r * 2048];
                sreg[jt][r] = s[r] + (mv ? bv : NEGBIG);
            }
        }

        float alpha[4];
        #pragma unroll
        for (int r = 0; r < 4; ++r) {
            float mx = fmaxf(fmaxf(sreg[0][r], sreg[1][r]), fmaxf(sreg[2][r], sreg[3][r]));
            mx = rowmax16(mx);
            float mnew = fmaxf(m_r[r], mx);
            alpha[r] = __expf(m_r[r] - mnew);
            m_r[r] = mnew;
            float ps = 0.f;
            #pragma unroll
            for (int jt = 0; jt < 4; ++jt) {
                float p = __expf(sreg[jt][r] - mnew);
                Pw[wave][quad * 4 + r][jt * 16 + l16] = (_Float16)p;
                ps += p;
            }
            ps = rowsum16(ps);
            l_r[r] = l_r[r] * alpha[r] + ps;
        }
        #pragma unroll
        for (int nt = 0; nt < 4; ++nt)
            #pragma unroll
            for (int r = 0; r < 4; ++r)
                o[nt][r] *= alpha[r];

        half8 pf0 = *(const half8*)&Pw[wave][l16][quad * 8];
        half8 pf1 = *(const half8*)&Pw[wave][l16][32 + quad * 8];
        #pragma unroll
        for (int nt = 0; nt < 4; ++nt) {
            half8 vf0 = *(const half8*)&Vt[nt * 16 + l16][quad * 8];
            half8 vf1 = *(const half8*)&Vt[nt * 16 + l16][32 + quad * 8];
            o[nt] = __builtin_amdgcn_mfma_f32_16x16x32_f16(pf0, vf0, o[nt], 0, 0, 0);
            o[nt] = __builtin_amdgcn_mfma_f32_16x16x32_f16(pf1, vf1, o[nt], 0, 0, 0);
        }
        __syncthreads();
    }

    #pragma unroll
    for (int nt = 0; nt < 4; ++nt) {
        #pragma unroll
        for (int r = 0; r < 4; ++r) {
            float val = o[nt][r] / l_r[r];
            AO[(size_t)(b * 2048 + i_base + quad * 4 + r) * 1024 + h * 64 + nt * 16 + l16] = (_Float16)val;
        }
    }
}

// ---------------- output projection: AO[4096][1024]f16 @ woT -> f32 out ----------------
__global__ __launch_bounds__(256)
void gemm_out_kernel(const _Float16* __restrict__ A, const _Float16* __restrict__ Bt,
                     float* __restrict__ C)
{
    __shared__ _Float16 Asb[128][40];
    __shared__ _Float16 Bsb[128][40];

    const int tid = threadIdx.x;
    const int bm = blockIdx.x * 128;
    const int bn = blockIdx.y * 128;
    const int wave = tid >> 6, lane = tid & 63;
    const int wm = (wave >> 1) * 64, wn = (wave & 1) * 64;
    const int quad = lane >> 4, l16 = lane & 15;

    f32x4 acc[4][4] = {};

    for (int k0 = 0; k0 < 1024; k0 += 32) {
        #pragma unroll
        for (int c = 0; c < 2; ++c) {
            int chunk = tid + c * 256;
            int row = chunk >> 2;
            int kc  = (chunk & 3) * 8;
            *(half8*)&Asb[row][kc] = *(const half8*)&A [(size_t)(bm + row) * 1024 + k0 + kc];
            *(half8*)&Bsb[row][kc] = *(const half8*)&Bt[(size_t)(bn + row) * 1024 + k0 + kc];
        }
        __syncthreads();
        half8 af[4], bf[4];
        #pragma unroll
        for (int mt = 0; mt < 4; ++mt) af[mt] = *(const half8*)&Asb[wm + mt*16 + l16][quad * 8];
        #pragma unroll
        for (int nt = 0; nt < 4; ++nt) bf[nt] = *(const half8*)&Bsb[wn + nt*16 + l16][quad * 8];
        #pragma unroll
        for (int mt = 0; mt < 4; ++mt)
            #pragma unroll
            for (int nt = 0; nt < 4; ++nt)
                acc[mt][nt] = __builtin_amdgcn_mfma_f32_16x16x32_f16(af[mt], bf[nt], acc[mt][nt], 0, 0, 0);
        __syncthreads();
    }

    #pragma unroll
    for (int mt = 0; mt < 4; ++mt)
        #pragma unroll
        for (int nt = 0; nt < 4; ++nt)
            #pragma unroll
            for (int r = 0; r < 4; ++r) {
                int m = bm + wm + mt * 16 + quad * 4 + r;
                int n = bn + wn + nt * 16 + l16;
                C[(size_t)m * 1024 + n] = acc[mt][nt][r];
            }
}

extern "C" void kernel_launch(void* const* d_in, const int* in_sizes, int n_in,
                              void* d_out, int out_size, void* d_ws, size_t ws_size,
                              hipStream_t stream)
{
    const float* x    = (const float*)d_in[0];
    const float* bias = (const float*)d_in[1];
    const int*   mask = (const int*)d_in[2];
    const float* wq   = (const float*)d_in[3];
    const float* wk   = (const float*)d_in[4];
    const float* wv   = (const float*)d_in[5];
    const float* wo   = (const float*)d_in[6];
    float* out = (float*)d_out;

    char* ws = (char*)d_ws;
    const size_t MB = 1024 * 1024;
    _Float16* x_h = (_Float16*)(ws + 0);        // 8 MB; reused as AO after QKV GEMMs
    _Float16* AO  = x_h;
    _Float16* wqT = (_Float16*)(ws + 8 * MB);
    _Float16* wkT = (_Float16*)(ws + 10 * MB);
    _Float16* wvT = (_Float16*)(ws + 12 * MB);
    _Float16* woT = (_Float16*)(ws + 14 * MB);
    _Float16* Qh  = (_Float16*)(ws + 16 * MB);  // [b][h][l][d]
    _Float16* Kh  = (_Float16*)(ws + 24 * MB);  // [b][h][l][d]
    _Float16* VTh = (_Float16*)(ws + 32 * MB);  // [b][h][d][l] (ends at 40 MB)

    cast4_kernel<<<4096, 256, 0, stream>>>(x, x_h, 4096 * 1024);
    dim3 tg(32, 32);
    transpose_cast_kernel<<<tg, 256, 0, stream>>>(wq, wqT);
    transpose_cast_kernel<<<tg, 256, 0, stream>>>(wk, wkT);
    transpose_cast_kernel<<<tg, 256, 0, stream>>>(wv, wvT);
    transpose_cast_kernel<<<tg, 256, 0, stream>>>(wo, woT);

    gemm_qkv_kernel<<<dim3(32, 8, 3), 256, 0, stream>>>(x_h, wqT, wkT, wvT, Qh, Kh, VTh);
    flash_attn_kernel<<<dim3(32, 16, 2), 256, 0, stream>>>(Qh, Kh, VTh, bias, mask, AO);
    gemm_out_kernel<<<dim3(32, 8), 256, 0, stream>>>(AO, woT, out);
}